// Round 18
// baseline (226.408 us; speedup 1.0000x reference)
//
#include <hip/hip_runtime.h>

typedef __attribute__((ext_vector_type(4))) float f32x4;
typedef __attribute__((ext_vector_type(8))) short bf16x8;
typedef __attribute__((ext_vector_type(4))) unsigned short u16x4;
typedef unsigned short u16;

#define MFMA16(a, b, c) __builtin_amdgcn_mfma_f32_16x16x32_bf16((a), (b), (c), 0, 0, 0)

#define T_SEQ 2048
#define DMODEL 2048
#define NHEADS 16
#define HDIM 128
#define WINDOW 256
#define MROWS 4096  // B*T
#define SC 0.08838834764831845f  // 1/sqrt(128)

__device__ __forceinline__ u16 f2bf(float f) {
  union { float f; unsigned u; } v; v.f = f;
  return (u16)((v.u + 0x7FFFu + ((v.u >> 16) & 1u)) >> 16);
}
__device__ __forceinline__ float bf2f(u16 u) {
  union { unsigned u; float f; } v; v.u = ((unsigned)u) << 16;
  return v.f;
}
__device__ __forceinline__ void gl_lds16(const u16* g, u16* l) {
  __builtin_amdgcn_global_load_lds((const __attribute__((address_space(1))) void*)(g),
                                   (__attribute__((address_space(3))) void*)(l), 16, 0, 0);
}

#define BAR __builtin_amdgcn_s_barrier()
#define FEN asm volatile("" ::: "memory")
#define VMC6 asm volatile("s_waitcnt vmcnt(6)" ::: "memory")
#define VMC4 asm volatile("s_waitcnt vmcnt(4)" ::: "memory")
#define VMC3 asm volatile("s_waitcnt vmcnt(3)" ::: "memory")
#define VMC0 asm volatile("s_waitcnt vmcnt(0)" ::: "memory")

// ---------------------------------------------------------------------------
// Convert x, Wq, Wk, Wv, Wo (f32) -> contiguous bf16: [xb NX][wq][wk][wv][wo]
// ---------------------------------------------------------------------------
__global__ __launch_bounds__(256) void convert_all(const float* __restrict__ x,
                                                   const float* __restrict__ wq,
                                                   const float* __restrict__ wk,
                                                   const float* __restrict__ wv,
                                                   const float* __restrict__ wo,
                                                   u16* __restrict__ dst) {
  const size_t NX = (size_t)MROWS * DMODEL;
  const size_t NW = (size_t)DMODEL * DMODEL;
  const size_t chunks = (NX + 4 * NW) / 8;
  for (size_t ci = (size_t)blockIdx.x * 256 + threadIdx.x; ci < chunks;
       ci += (size_t)gridDim.x * 256) {
    const size_t off = ci * 8;
    const float* src;
    size_t so;
    if (off < NX) { src = x; so = off; }
    else {
      size_t rem = off - NX;
      if (rem < NW) { src = wq; so = rem; }
      else if (rem < 2 * NW) { src = wk; so = rem - NW; }
      else if (rem < 3 * NW) { src = wv; so = rem - 2 * NW; }
      else { src = wo; so = rem - 3 * NW; }
    }
    f32x4 a = *(const f32x4*)&src[so];
    f32x4 b = *(const f32x4*)&src[so + 4];
    bf16x8 o;
#pragma unroll
    for (int j = 0; j < 4; ++j) { o[j] = (short)f2bf(a[j]); o[j + 4] = (short)f2bf(b[j]); }
    *(bf16x8*)&dst[off] = o;
  }
}

// ---------------------------------------------------------------------------
// 2-phase QKV GEMM, 3 blocks/CU: C[4096,6144] = A @ Wcat^T, all bf16.
// BM=128, BN=192, BK=32 (64 K-tiles). 256 thr = 4 waves (1m x 4n); per-wave
// 128x48 (8mi x 3ni), 24 MFMA/K-tile in 2 phases of 12.
// LDS 40 KB (A dbuf 2x8K, B dbuf 2x12K) -> LDS-limit 4 blocks/CU, VGPR-limit
// ~3 -> 3 independent barrier domains/CU (m114 coverage, proven R17 lever).
// Line-pair layout: 128B line = rows {2r,2r+1}; granule slot =
// ((row&1)*4 + g) ^ (lineRow&7). Read lanes hit each bank-quad exactly 2x
// (free); lineRow&7 is mi-invariant so read offset is one per-lane constant.
// 5 gl_lds/thr/K-tile (A:2, B:3). Ledger (pair t0=2i -> buf0, t0+1 -> buf1):
//  Ph1: rd AL+B(b0) | SA(t0+1)->b1 | BAR | 12 MFMA | BAR
//  Ph2: rd AH(b0)   | SB(t0+2)->b0 | VMC3 (forces t0+1, leaves B(t0+2)) ...
//  Ph3: rd AL+B(b1) | SA(t0+2)->b0 | BAR | 12 MFMA | BAR
//  Ph4: rd AH(b1)   | SB(t0+3)->b1 | VMC3 (forces t0+2) | BAR | 12 MFMA | BAR
// Tail t=62/63 drains with VMC0. Grid 1024 = 8 xcd x (32 mt x 4-nt slice).
// Epilogue: qb[4096][2048] (Q pre-scaled), kb[bh][t][128], vb[bh][kt][d][64].
// ---------------------------------------------------------------------------
__global__ __launch_bounds__(256, 3) void gemm_qkv(const u16* __restrict__ A,
                                                   const u16* __restrict__ W,
                                                   u16* __restrict__ qb,
                                                   u16* __restrict__ kb,
                                                   u16* __restrict__ vb) {
  __shared__ u16 lds[20480];  // A: [0,8192) 2x4096; B: [8192,20480) 2x6144
  const int tid = threadIdx.x, w = tid >> 6, lane = tid & 63;
  const int fr = lane & 15, g = lane >> 4, g4 = g * 4;

  const int xcd = blockIdx.x & 7, bi = blockIdx.x >> 3;  // bi 0..127
  const int mt = bi >> 2, nt = xcd * 4 + (bi & 3);
  const int m0 = mt * 128, n0 = nt * 192;

  // frag-read swizzled slot (u16 offset within 128B line-pair), mi-invariant
  const int xsA = ((((fr & 1) * 4 + g) ^ (fr >> 1)) << 3);
  const int frh = fr >> 1;

  // staging sources: granule gi = j*256+tid; lineRow=gi>>3, slot=gi&7;
  // sub = slot ^ (lineRow&7); row = lineRow*2 + (sub>>2); col = (sub&3)*8
  const u16* pA[2];
  const u16* pB[3];
#pragma unroll
  for (int j = 0; j < 2; ++j) {
    const int gi = j * 256 + tid, lr = gi >> 3, sl = gi & 7;
    const int sub = sl ^ (lr & 7), row = lr * 2 + (sub >> 2), col = (sub & 3) * 8;
    pA[j] = A + (size_t)(m0 + row) * DMODEL + col;
  }
#pragma unroll
  for (int j = 0; j < 3; ++j) {
    const int gi = j * 256 + tid, lr = gi >> 3, sl = gi & 7;
    const int sub = sl ^ (lr & 7), row = lr * 2 + (sub >> 2), col = (sub & 3) * 8;
    pB[j] = W + (size_t)(n0 + row) * DMODEL + col;
  }

#define SA(t, c)                                                                       \
  { _Pragma("unroll") for (int j = 0; j < 2; ++j)                                      \
      gl_lds16(pA[j] + (t) * 32, &lds[(c) * 4096 + j * 2048 + w * 512]); }
#define SB(t, c)                                                                       \
  { _Pragma("unroll") for (int j = 0; j < 3; ++j)                                      \
      gl_lds16(pB[j] + (t) * 32, &lds[8192 + (c) * 6144 + j * 2048 + w * 512]); }

#define RD_AL(c)                                                                       \
  { _Pragma("unroll") for (int m_ = 0; m_ < 4; ++m_)                                   \
      af[m_] = *(const bf16x8*)&lds[(c) * 4096 + (frh + m_ * 8) * 64 + xsA]; }
#define RD_AH(c)                                                                       \
  { _Pragma("unroll") for (int m_ = 0; m_ < 4; ++m_)                                   \
      af[m_] = *(const bf16x8*)&lds[(c) * 4096 + (frh + 32 + m_ * 8) * 64 + xsA]; }
#define RD_B(c)                                                                        \
  { _Pragma("unroll") for (int n_ = 0; n_ < 3; ++n_)                                   \
      bfr[n_] = *(const bf16x8*)&lds[8192 + (c) * 6144 + (w * 24 + n_ * 8 + frh) * 64 + xsA]; }

#define MMQ(MB)                                                                        \
  { __builtin_amdgcn_s_setprio(1);                                                    \
    _Pragma("unroll") for (int m_ = 0; m_ < 4; ++m_)                                   \
      _Pragma("unroll") for (int n_ = 0; n_ < 3; ++n_)                                 \
        acc[(MB) + m_][n_] = MFMA16(af[m_], bfr[n_], acc[(MB) + m_][n_]);              \
    __builtin_amdgcn_s_setprio(0); }

  bf16x8 af[4], bfr[3];
  f32x4 acc[8][3];
#pragma unroll
  for (int i = 0; i < 8; ++i)
#pragma unroll
    for (int j = 0; j < 3; ++j) acc[i][j] = (f32x4){0.f, 0.f, 0.f, 0.f};

  // prologue: tile0 -> buf0 (5 loads); B(1) -> buf1 (3); VMC3 forces tile0
  SA(0, 0); SB(0, 0);
  SB(1, 1);
  VMC3; BAR;

#pragma unroll 1
  for (int i = 0; i < 31; ++i) {
    const int t0 = 2 * i;
    // tile t0 (buf0)
    RD_AL(0); RD_B(0); SA(t0 + 1, 1);
    FEN; BAR; MMQ(0); FEN; BAR;
    RD_AH(0); SB(t0 + 2, 0);
    VMC3; BAR; MMQ(4); FEN; BAR;
    // tile t0+1 (buf1)
    RD_AL(1); RD_B(1); SA(t0 + 2, 0);
    FEN; BAR; MMQ(0); FEN; BAR;
    RD_AH(1); SB(t0 + 3, 1);
    VMC3; BAR; MMQ(4); FEN; BAR;
  }
  // tail: t=62 (buf0), t=63 (buf1)
  RD_AL(0); RD_B(0); SA(63, 1);
  FEN; BAR; MMQ(0); FEN; BAR;
  RD_AH(0);
  VMC0; BAR; MMQ(4); FEN; BAR;
  RD_AL(1); RD_B(1);
  FEN; BAR; MMQ(0); FEN; BAR;
  RD_AH(1);
  FEN; BAR; MMQ(4);

  // epilogue: row = m0 + mi*16 + g4 + r, col = n0 + w*48 + ni*16 + fr
#pragma unroll
  for (int mi = 0; mi < 8; ++mi)
#pragma unroll
    for (int ni = 0; ni < 3; ++ni) {
      const int row0 = m0 + mi * 16 + g4;
      const int cg = n0 + w * 48 + ni * 16 + fr;
      const int bb = row0 >> 11, tl = row0 & 2047;
      if (cg < DMODEL) {
        // Q, pre-scaled
#pragma unroll
        for (int r = 0; r < 4; ++r)
          qb[(size_t)(row0 + r) * DMODEL + cg] = f2bf(acc[mi][ni][r] * SC);
      } else if (cg < 2 * DMODEL) {
        // K -> compact [bh][t][128]
        const int cc = cg - DMODEL;
        const int hh = cc >> 7, d = cc & 127;
        const size_t kbase = (size_t)(bb * NHEADS + hh) * T_SEQ * HDIM;
#pragma unroll
        for (int r = 0; r < 4; ++r)
          kb[kbase + (size_t)(tl + r) * HDIM + d] = f2bf(acc[mi][ni][r]);
      } else {
        // V -> tile-blocked [bh][kt][d][64]
        const int cc = cg - 2 * DMODEL;
        const int hh = cc >> 7, d = cc & 127;
        u16x4 w4;
#pragma unroll
        for (int r = 0; r < 4; ++r) w4[r] = f2bf(acc[mi][ni][r]);
        *(u16x4*)&vb[(size_t)(bb * NHEADS + hh) * T_SEQ * HDIM + (size_t)(tl >> 6) * 8192 +
                     d * 64 + (tl & 63)] = w4;
      }
    }
#undef SA
#undef SB
#undef RD_AL
#undef RD_AH
#undef RD_B
#undef MMQ
}

// ---------------------------------------------------------------------------
// 2-phase out-proj GEMM, 2 blocks/CU (R17 winner, unchanged).
// ---------------------------------------------------------------------------
__global__ __launch_bounds__(256, 2) void gemm_out(const u16* __restrict__ A,
                                                   const u16* __restrict__ W0,
                                                   float* __restrict__ outf) {
  __shared__ u16 lds2[32768];  // A: [0,16384); B: [16384,32768)
  const int tid = threadIdx.x, w = tid >> 6, lane = tid & 63;
  const int fr = lane & 15, g = lane >> 4, g4 = g * 4;
  const int xk = fr & 7;

  const int xcd = blockIdx.x & 7, bi = blockIdx.x >> 3;  // bi 0..63
  const int mt = bi >> 1, nt = xcd * 2 + (bi & 1);
  const int m0 = mt * 128, n0 = nt * 128;

  const int xs0 = (g ^ xk) * 8;
  const int xs1 = xs0 ^ 32;
  const int bRow = w * 32 + fr;

  const u16* pA[4];
  const u16* pB[4];
#pragma unroll
  for (int j = 0; j < 4; ++j) {
    const int gi = j * 256 + tid, row = gi >> 3, ch = (gi & 7) ^ (row & 7);
    pA[j] = A + (size_t)(m0 + row) * DMODEL + ch * 8;
    pB[j] = W0 + (size_t)(n0 + row) * DMODEL + ch * 8;
  }

#define S2A(t, c)                                                                      \
  { _Pragma("unroll") for (int j = 0; j < 4; ++j)                                      \
      gl_lds16(pA[j] + (size_t)(t) * 64, &lds2[(c) * 8192 + j * 2048 + w * 512]); }
#define S2B(t, c)                                                                      \
  { _Pragma("unroll") for (int j = 0; j < 4; ++j)                                      \
      gl_lds16(pB[j] + (size_t)(t) * 64, &lds2[16384 + (c) * 8192 + j * 2048 + w * 512]); }

#define R2AL(c)                                                                        \
  { _Pragma("unroll") for (int m_ = 0; m_ < 4; ++m_) {                                 \
      af[m_][0] = *(const bf16x8*)&lds2[(c) * 8192 + (fr + m_ * 16) * 64 + xs0];       \
      af[m_][1] = *(const bf16x8*)&lds2[(c) * 8192 + (fr + m_ * 16) * 64 + xs1]; } }
#define R2AH(c)                                                                        \
  { _Pragma("unroll") for (int m_ = 0; m_ < 4; ++m_) {                                 \
      af[m_][0] = *(const bf16x8*)&lds2[(c) * 8192 + (fr + 64 + m_ * 16) * 64 + xs0];  \
      af[m_][1] = *(const bf16x8*)&lds2[(c) * 8192 + (fr + 64 + m_ * 16) * 64 + xs1]; } }
#define R2B(c)                                                                         \
  { _Pragma("unroll") for (int n_ = 0; n_ < 2; ++n_) {                                 \
      bfr[n_][0] = *(const bf16x8*)&lds2[16384 + (c) * 8192 + (bRow + n_ * 16) * 64 + xs0]; \
      bfr[n_][1] = *(const bf16x8*)&lds2[16384 + (c) * 8192 + (bRow + n_ * 16) * 64 + xs1]; } }

#define M2(MB)                                                                         \
  { __builtin_amdgcn_s_setprio(1);                                                    \
    _Pragma("unroll") for (int kc_ = 0; kc_ < 2; ++kc_)                                \
      _Pragma("unroll") for (int m_ = 0; m_ < 4; ++m_)                                 \
        _Pragma("unroll") for (int n_ = 0; n_ < 2; ++n_)                               \
          acc[(MB) + m_][n_] = MFMA16(af[m_][kc_], bfr[n_][kc_], acc[(MB) + m_][n_]);  \
    __builtin_amdgcn_s_setprio(0); }

  bf16x8 af[4][2], bfr[2][2];
  f32x4 acc[8][2];
#pragma unroll
  for (int i = 0; i < 8; ++i)
#pragma unroll
    for (int j = 0; j < 2; ++j) acc[i][j] = (f32x4){0.f, 0.f, 0.f, 0.f};

  S2A(0, 0); S2B(0, 0);
  S2B(1, 1);
  VMC4; BAR;

#pragma unroll 1
  for (int i = 0; i < 15; ++i) {
    const int t0 = 2 * i;
    R2AL(0); R2B(0); S2A(t0 + 1, 1);
    FEN; BAR; M2(0); FEN; BAR;
    R2AH(0); S2B(t0 + 2, 0);
    VMC4; BAR; M2(4); FEN; BAR;
    R2AL(1); R2B(1); S2A(t0 + 2, 0);
    FEN; BAR; M2(0); FEN; BAR;
    R2AH(1); S2B(t0 + 3, 1);
    VMC4; BAR; M2(4); FEN; BAR;
  }
  R2AL(0); R2B(0); S2A(31, 1);
  FEN; BAR; M2(0); FEN; BAR;
  R2AH(0);
  VMC0; BAR; M2(4); FEN; BAR;
  R2AL(1); R2B(1);
  FEN; BAR; M2(0); FEN; BAR;
  R2AH(1);
  FEN; BAR; M2(4);

#pragma unroll
  for (int mi = 0; mi < 8; ++mi)
#pragma unroll
    for (int ni = 0; ni < 2; ++ni) {
      const int row0 = m0 + mi * 16 + g4;
      const int c = n0 + w * 32 + ni * 16 + fr;
#pragma unroll
      for (int r = 0; r < 4; ++r)
        outf[(size_t)(row0 + r) * DMODEL + c] = acc[mi][ni][r];
    }
#undef S2A
#undef S2B
#undef R2AL
#undef R2AH
#undef R2B
#undef M2
}

// ---------------------------------------------------------------------------
// Striped flash attention (R16 winner, byte-identical): XCD-locality mapping.
// Grid 768 = 8 xcd x 4 (b,h) pairs x 24 bx; co-resident blocks on one XCD
// share <=4 MB of K/V (L2-resident).
// ---------------------------------------------------------------------------
#define QB 128
#define KVB 64

__global__ __launch_bounds__(512, 4) void attn_kernel(const u16* __restrict__ qb,
                                                      const u16* __restrict__ kb,
                                                      const u16* __restrict__ vb,
                                                      u16* __restrict__ op,
                                                      u16* __restrict__ pO,
                                                      float* __restrict__ pm,
                                                      float* __restrict__ pl) {
  __shared__ u16 lds[40960];  // 80 KB

  const int xcdid = blockIdx.x & 7, j = blockIdx.x >> 3;
  const int p = xcdid * 4 + j / 24;  // (b,h) pair 0..63
  const int bx = j % 24;
  const int h = p & 15, b = p >> 4;

  const bool isglobal = (h & 1) == 0;
  int qt, klo, khi, part = 0;
  bool partial = false;
  if (isglobal) {
    if (bx < 16) {
      qt = 15 - (bx >> 1);
      part = bx & 1;
      partial = true;
      if (part == 0) { klo = 0; khi = 15; } else { klo = 16; khi = 2 * qt + 1; }
    } else {
      qt = 23 - bx;  // 0..7
      klo = 0; khi = 2 * qt + 1;
    }
  } else {
    if (bx >= 16) return;
    qt = 15 - bx;
    const int lo_ = qt * QB - (WINDOW - 1);
    klo = lo_ > 0 ? (lo_ >> 6) : 0;
    khi = 2 * qt + 1;
  }

  const int tid = threadIdx.x, wave = tid >> 6, lane = tid & 63;
  const int fr = lane & 15, g = lane >> 4, g4 = g * 4;
  const int xk = fr & 7;
  const int q0 = qt * QB;
  const int bh = b * NHEADS + h;
  const size_t basek = (size_t)bh * T_SEQ * HDIM;
  const size_t baseo = (size_t)b * T_SEQ * DMODEL + (size_t)h * HDIM;

  bf16x8 qf[4];
  {
    const int qrow = q0 + wave * 16 + fr;
#pragma unroll
    for (int ds = 0; ds < 4; ++ds)
      qf[ds] = *(const bf16x8*)&qb[(size_t)b * T_SEQ * DMODEL + (size_t)qrow * DMODEL +
                                   (size_t)h * HDIM + ds * 32 + g * 8];
  }

  float mrun = -1e30f, lrun = 0.f;
  f32x4 o[8];
#pragma unroll
  for (int dt = 0; dt < 8; ++dt) o[dt] = (f32x4){0.f, 0.f, 0.f, 0.f};

  const int j0 = wave * 2, j1 = wave * 2 + 1;
  const int gi0 = j0 * 64 + lane, gi1 = j1 * 64 + lane;
  const int kr0 = gi0 >> 4, kc0 = (gi0 & 15) ^ (kr0 & 7);
  const int kr1 = gi1 >> 4, kc1 = (gi1 & 15) ^ (kr1 & 7);
  const u16* pK0 = kb + basek + (size_t)kr0 * HDIM + kc0 * 8;
  const u16* pK1 = kb + basek + (size_t)kr1 * HDIM + kc1 * 8;
  const int d0 = gi0 >> 3, vs0 = (gi0 & 7) ^ (d0 & 7);
  const int d1 = gi1 >> 3, vs1 = (gi1 & 7) ^ (d1 & 7);
  const u16* pV0 = vb + basek + (size_t)d0 * 64 + vs0 * 8;
  const u16* pV1 = vb + basek + (size_t)d1 * 64 + vs1 * 8;

#define STAGE(KT, c)                                                                   \
  { gl_lds16(pK0 + (size_t)(KT) * 8192, &lds[(c) * 8192 + j0 * 512]);                  \
    gl_lds16(pK1 + (size_t)(KT) * 8192, &lds[(c) * 8192 + j1 * 512]);                  \
    gl_lds16(pV0 + (size_t)(KT) * 8192, &lds[16384 + (c) * 8192 + j0 * 512]);          \
    gl_lds16(pV1 + (size_t)(KT) * 8192, &lds[16384 + (c) * 8192 + j1 * 512]); }

  u16* Pw = &lds[32768 + wave * 1024];
  const int qg = q0 + wave * 16 + fr;

  STAGE(klo, klo & 1);
  VMC0; BAR;

  for (int kt = klo; kt <= khi; ++kt) {
    const int c = kt & 1;
    const bool more = kt < khi;
    if (more) STAGE(kt + 1, c ^ 1);
    const u16* Kc = &lds[c * 8192];
    const u16* Vc = &lds[16384 + c * 8192];

    f32x4 s[4];
    __builtin_amdgcn_s_setprio(1);
#pragma unroll
    for (int kk = 0; kk < 4; ++kk) {
      f32x4 a = (f32x4){0.f, 0.f, 0.f, 0.f};
#pragma unroll
      for (int ds = 0; ds < 4; ++ds) {
        const int r = kk * 16 + fr;
        bf16x8 kf = *(const bf16x8*)&Kc[r * 128 + (((ds * 4 + g) ^ xk) << 3)];
        a = MFMA16(kf, qf[ds], a);
      }
      s[kk] = a;
    }
    __builtin_amdgcn_s_setprio(0);

    float sv[16];
    float pmax = -1e30f;
#pragma unroll
    for (int kk = 0; kk < 4; ++kk)
#pragma unroll
      for (int reg = 0; reg < 4; ++reg) {
        const int cg = kt * KVB + kk * 16 + g4 + reg;
        const bool allowed = (cg <= qg) && (isglobal || cg >= qg - (WINDOW - 1));
        const float v = allowed ? s[kk][reg] : -1e30f;
        sv[kk * 4 + reg] = v;
        pmax = fmaxf(pmax, v);
      }
    pmax = fmaxf(pmax, __shfl_xor(pmax, 16, 64));
    pmax = fmaxf(pmax, __shfl_xor(pmax, 32, 64));
    const bool resc = !__all(pmax - mrun <= 8.0f);  // T13
    float fac = 1.f;
    if (resc) {
      const float nm = fmaxf(mrun, pmax);
      fac = __expf(mrun - nm);
      mrun = nm;
    }
    float rs = 0.f;
    u16 pb[16];
#pragma unroll
    for (int i = 0; i < 16; ++i) {
      const float p_ = (sv[i] > -5e29f) ? __expf(sv[i] - mrun) : 0.f;
      rs += p_;
      pb[i] = f2bf(p_);
    }
    rs += __shfl_xor(rs, 16, 64);
    rs += __shfl_xor(rs, 32, 64);
    lrun = lrun * fac + rs;

#pragma unroll
    for (int kk = 0; kk < 4; ++kk) {
      u16x4 wv;
      wv[0] = pb[kk * 4]; wv[1] = pb[kk * 4 + 1]; wv[2] = pb[kk * 4 + 2]; wv[3] = pb[kk * 4 + 3];
      *(u16x4*)&Pw[fr * 64 + (((2 * kk + (g >> 1)) ^ xk) << 3) + (g & 1) * 4] = wv;
    }

    if (resc) {
      float ff[4];
#pragma unroll
      for (int r = 0; r < 4; ++r) ff[r] = __shfl(fac, g4 + r, 64);
#pragma unroll
      for (int dt = 0; dt < 8; ++dt)
#pragma unroll
        for (int r = 0; r < 4; ++r) o[dt][r] *= ff[r];
    }

    bf16x8 pf0 = *(const bf16x8*)&Pw[fr * 64 + ((g ^ xk) << 3)];
    bf16x8 pf1 = *(const bf16x8*)&Pw[fr * 64 + (((4 + g) ^ xk) << 3)];
    __builtin_amdgcn_s_setprio(1);
#pragma unroll
    for (int dt = 0; dt < 8; ++dt) {
      const int d = dt * 16 + fr;
      bf16x8 vf0 = *(const bf16x8*)&Vc[d * 64 + ((g ^ xk) << 3)];
      bf16x8 vf1 = *(const bf16x8*)&Vc[d * 64 + (((4 + g) ^ xk) << 3)];
      o[dt] = MFMA16(pf0, vf0, o[dt]);
      o[dt] = MFMA16(pf1, vf1, o[dt]);
    }
    __builtin_amdgcn_s_setprio(0);

    FEN;
    VMC0;
    BAR;
  }

  if (!partial) {
    const float inv = 1.0f / lrun;
    float iv[4];
#pragma unroll
    for (int r = 0; r < 4; ++r) iv[r] = __shfl(inv, g4 + r, 64);
#pragma unroll
    for (int r = 0; r < 4; ++r) {
      const int qrow = q0 + wave * 16 + g4 + r;
#pragma unroll
      for (int dt = 0; dt < 8; ++dt)
        op[baseo + (size_t)qrow * DMODEL + dt * 16 + fr] = f2bf(o[dt][r] * iv[r]);
    }
  } else {
    const int sidx = (((b * 8 + (h >> 1)) * 8 + (qt - 8)) << 1) + part;
    const size_t sb = (size_t)sidx * QB;
#pragma unroll
    for (int r = 0; r < 4; ++r) {
      const size_t row = sb + wave * 16 + g4 + r;
#pragma unroll
      for (int dt = 0; dt < 8; ++dt)
        pO[row * HDIM + dt * 16 + fr] = f2bf(o[dt][r]);
    }
    if (lane < 16) {
      pm[sb + wave * 16 + lane] = mrun;
      pl[sb + wave * 16 + lane] = lrun;
    }
  }
#undef STAGE
}

// ---------------------------------------------------------------------------
// Merge two partials per (b, even h, qt>=8). Grid 128 x 256 thr. Scaled dom.
// ---------------------------------------------------------------------------
__global__ __launch_bounds__(256) void merge_kernel(const u16* __restrict__ pO,
                                                    const float* __restrict__ pm,
                                                    const float* __restrict__ pl,
                                                    u16* __restrict__ op) {
  const int x = blockIdx.x;  // 0..127 = (b*8 + eh)*8 + qt8
  const int qt8 = x & 7, eh = (x >> 3) & 7, b = x >> 6;
  const int h = eh * 2, qt = 8 + qt8;
  const int s0 = x * 2, s1 = s0 + 1;

  for (int i = 0; i < 8; ++i) {
    const int vidx = threadIdx.x + i * 256;  // 0..2047
    const int row = vidx >> 4, d8 = (vidx & 15) * 8;
    const float m0 = pm[s0 * QB + row], m1 = pm[s1 * QB + row];
    const float l0 = pl[s0 * QB + row], l1 = pl[s1 * QB + row];
    const float m = fmaxf(m0, m1);
    const float w0 = __expf(m0 - m), w1 = __expf(m1 - m);
    const float inv = 1.0f / (l0 * w0 + l1 * w1);
    bf16x8 a = *(const bf16x8*)&pO[((size_t)s0 * QB + row) * HDIM + d8];
    bf16x8 c = *(const bf16x8*)&pO[((size_t)s1 * QB + row) * HDIM + d8];
    bf16x8 r;
#pragma unroll
    for (int j = 0; j < 8; ++j)
      r[j] = (short)f2bf((bf2f((u16)a[j]) * w0 + bf2f((u16)c[j]) * w1) * inv);
    *(bf16x8*)&op[((size_t)(b * T_SEQ + qt * QB + row)) * DMODEL + h * HDIM + d8] = r;
  }
}

// ---------------------------------------------------------------------------
extern "C" void kernel_launch(void* const* d_in, const int* in_sizes, int n_in,
                              void* d_out, int out_size, void* d_ws, size_t ws_size,
                              hipStream_t stream) {
  (void)in_sizes; (void)n_in; (void)out_size; (void)ws_size;
  const float* x  = (const float*)d_in[0];
  const float* Wq = (const float*)d_in[1];
  const float* Wk = (const float*)d_in[2];
  const float* Wv = (const float*)d_in[3];
  const float* Wo = (const float*)d_in[4];

  const size_t NX = (size_t)MROWS * DMODEL;
  const size_t NW = (size_t)DMODEL * DMODEL;
  u16* ws  = (u16*)d_ws;
  u16* xb  = ws;                 // bf16 x; later attention output
  u16* wqb = ws + NX;            // [wq|wk|wv] contiguous = Wcat[6144][2048]
  u16* wkb = wqb + NW;
  u16* wvb = wkb + NW;
  u16* wob = wvb + NW;
  u16* qbb = wob + NW;           // qb [4096][2048]
  u16* kbb = qbb + NX;           // kb [32][2048][128]
  u16* vbb = kbb + NX;           // vb [32][32][128][64]

  // partials reuse dead wq/wk region: 256 slots x 128 rows x 128 d
  u16*   pO = wqb;
  float* pm = (float*)(wqb + (size_t)256 * QB * HDIM);
  float* pl = pm + 256 * QB;

  convert_all<<<2048, 256, 0, stream>>>(x, Wq, Wk, Wv, Wo, ws);

  gemm_qkv<<<1024, 256, 0, stream>>>(xb, wqb, qbb, kbb, vbb);

  attn_kernel<<<768, 512, 0, stream>>>(qbb, kbb, vbb, xb, pO, pm, pl);

  merge_kernel<<<128, 256, 0, stream>>>(pO, pm, pl, xb);

  gemm_out<<<512, 256, 0, stream>>>(xb, wob, (float*)d_out);
}

// Round 19
// 210.841 us; speedup vs baseline: 1.0738x; 1.0738x over previous
//
#include <hip/hip_runtime.h>

typedef __attribute__((ext_vector_type(4))) float f32x4;
typedef __attribute__((ext_vector_type(8))) short bf16x8;
typedef __attribute__((ext_vector_type(4))) unsigned short u16x4;
typedef unsigned short u16;

#define MFMA16(a, b, c) __builtin_amdgcn_mfma_f32_16x16x32_bf16((a), (b), (c), 0, 0, 0)

#define T_SEQ 2048
#define DMODEL 2048
#define NHEADS 16
#define HDIM 128
#define WINDOW 256
#define MROWS 4096  // B*T
#define SC 0.08838834764831845f  // 1/sqrt(128)

__device__ __forceinline__ u16 f2bf(float f) {
  union { float f; unsigned u; } v; v.f = f;
  return (u16)((v.u + 0x7FFFu + ((v.u >> 16) & 1u)) >> 16);
}
__device__ __forceinline__ float bf2f(u16 u) {
  union { unsigned u; float f; } v; v.u = ((unsigned)u) << 16;
  return v.f;
}
__device__ __forceinline__ void gl_lds16(const u16* g, u16* l) {
  __builtin_amdgcn_global_load_lds((const __attribute__((address_space(1))) void*)(g),
                                   (__attribute__((address_space(3))) void*)(l), 16, 0, 0);
}

#define BAR __builtin_amdgcn_s_barrier()
#define FEN asm volatile("" ::: "memory")
#define VMC6 asm volatile("s_waitcnt vmcnt(6)" ::: "memory")
#define VMC4 asm volatile("s_waitcnt vmcnt(4)" ::: "memory")
#define VMC0 asm volatile("s_waitcnt vmcnt(0)" ::: "memory")

// ---------------------------------------------------------------------------
// Convert x, Wq, Wk, Wv, Wo (f32) -> contiguous bf16: [xb NX][wq][wk][wv][wo]
// ---------------------------------------------------------------------------
__global__ __launch_bounds__(256) void convert_all(const float* __restrict__ x,
                                                   const float* __restrict__ wq,
                                                   const float* __restrict__ wk,
                                                   const float* __restrict__ wv,
                                                   const float* __restrict__ wo,
                                                   u16* __restrict__ dst) {
  const size_t NX = (size_t)MROWS * DMODEL;
  const size_t NW = (size_t)DMODEL * DMODEL;
  const size_t chunks = (NX + 4 * NW) / 8;
  for (size_t ci = (size_t)blockIdx.x * 256 + threadIdx.x; ci < chunks;
       ci += (size_t)gridDim.x * 256) {
    const size_t off = ci * 8;
    const float* src;
    size_t so;
    if (off < NX) { src = x; so = off; }
    else {
      size_t rem = off - NX;
      if (rem < NW) { src = wq; so = rem; }
      else if (rem < 2 * NW) { src = wk; so = rem - NW; }
      else if (rem < 3 * NW) { src = wv; so = rem - 2 * NW; }
      else { src = wo; so = rem - 3 * NW; }
    }
    f32x4 a = *(const f32x4*)&src[so];
    f32x4 b = *(const f32x4*)&src[so + 4];
    bf16x8 o;
#pragma unroll
    for (int j = 0; j < 4; ++j) { o[j] = (short)f2bf(a[j]); o[j + 4] = (short)f2bf(b[j]); }
    *(bf16x8*)&dst[off] = o;
  }
}

// ---------------------------------------------------------------------------
// 2-phase QKV GEMM, 2 blocks/CU: C[4096,6144] = A @ Wcat^T, all bf16.
// BM=128, BN=192, BK=64. 256 thr = 4 waves (1m x 4n); per-wave 128x48
// (8mi x 3ni), 48 MFMA/K-tile/wave in 2 phases of 24.
// LDS 80 KB (A dbuf 2x16K, B dbuf 2x24K) -> 2 blocks/CU: two independent
// barrier domains per CU cover each other's drain stalls (m114 mechanism).
// Grid 1024 = 8 xcd x (32 mt x 4-nt slice); W slice 3 MB L2-fits; 2 rounds.
// 10 gl_lds/thr/K-tile (A:4, B:6). Ledger (tile t, buf c=t&1):
//  P1: rd AL+B | SA(t+1)->c^1 [+4 -> 10 out] | BAR | 24 MFMA | BAR
//  P2: rd AH   | SB(t+2)->c   [+6 -> 16 out] | VMC6 | BAR | 24 MFMA | BAR
// VMC6 forces oldest 10 = B(t+1)+A(t+1); leaves B(t+2). Tail t=30: VMC0.
// Epilogue: qb[4096][2048] (Q pre-scaled), kb[bh][t][128], vb[bh][kt][d][64].
// ---------------------------------------------------------------------------
__global__ __launch_bounds__(256, 2) void gemm_qkv(const u16* __restrict__ A,
                                                   const u16* __restrict__ W,
                                                   u16* __restrict__ qb,
                                                   u16* __restrict__ kb,
                                                   u16* __restrict__ vb) {
  __shared__ u16 lds[40960];  // A: [0,16384) u16; B: [16384,40960) u16
  const int tid = threadIdx.x, w = tid >> 6, lane = tid & 63;
  const int fr = lane & 15, g = lane >> 4, g4 = g * 4;
  const int xk = fr & 7;

  const int xcd = blockIdx.x & 7, bi = blockIdx.x >> 3;  // bi 0..127
  const int mt = bi >> 2, nt = xcd * 4 + (bi & 3);
  const int m0 = mt * 128, n0 = nt * 192;

  const int xs0 = (g ^ xk) * 8;
  const int xs1 = xs0 ^ 32;
  const int bRow = w * 48 + fr;

  // staging sources (pre-swizzled: chunk = slot ^ (row&7))
  const u16* pA[4];
  const u16* pB[6];
#pragma unroll
  for (int j = 0; j < 4; ++j) {
    const int gi = j * 256 + tid, row = gi >> 3, ch = (gi & 7) ^ (row & 7);
    pA[j] = A + (size_t)(m0 + row) * DMODEL + ch * 8;
  }
#pragma unroll
  for (int j = 0; j < 6; ++j) {
    const int gi = j * 256 + tid, row = gi >> 3, ch = (gi & 7) ^ (row & 7);
    pB[j] = W + (size_t)(n0 + row) * DMODEL + ch * 8;
  }

#define SA(t, c)                                                                       \
  { _Pragma("unroll") for (int j = 0; j < 4; ++j)                                      \
      gl_lds16(pA[j] + (size_t)(t) * 64, &lds[(c) * 8192 + j * 2048 + w * 512]); }
#define SB(t, c)                                                                       \
  { _Pragma("unroll") for (int j = 0; j < 6; ++j)                                      \
      gl_lds16(pB[j] + (size_t)(t) * 64, &lds[16384 + (c) * 12288 + j * 2048 + w * 512]); }

#define RD_AL(c)                                                                       \
  { _Pragma("unroll") for (int m_ = 0; m_ < 4; ++m_) {                                 \
      af[m_][0] = *(const bf16x8*)&lds[(c) * 8192 + (fr + m_ * 16) * 64 + xs0];        \
      af[m_][1] = *(const bf16x8*)&lds[(c) * 8192 + (fr + m_ * 16) * 64 + xs1]; } }
#define RD_AH(c)                                                                       \
  { _Pragma("unroll") for (int m_ = 0; m_ < 4; ++m_) {                                 \
      af[m_][0] = *(const bf16x8*)&lds[(c) * 8192 + (fr + 64 + m_ * 16) * 64 + xs0];   \
      af[m_][1] = *(const bf16x8*)&lds[(c) * 8192 + (fr + 64 + m_ * 16) * 64 + xs1]; } }
#define RD_B(c)                                                                        \
  { _Pragma("unroll") for (int n_ = 0; n_ < 3; ++n_) {                                 \
      bfr[n_][0] = *(const bf16x8*)&lds[16384 + (c) * 12288 + (bRow + n_ * 16) * 64 + xs0]; \
      bfr[n_][1] = *(const bf16x8*)&lds[16384 + (c) * 12288 + (bRow + n_ * 16) * 64 + xs1]; } }

#define MMQ(MB)                                                                        \
  { __builtin_amdgcn_s_setprio(1);                                                    \
    _Pragma("unroll") for (int kc_ = 0; kc_ < 2; ++kc_)                                \
      _Pragma("unroll") for (int m_ = 0; m_ < 4; ++m_)                                 \
        _Pragma("unroll") for (int n_ = 0; n_ < 3; ++n_)                               \
          acc[(MB) + m_][n_] = MFMA16(af[m_][kc_], bfr[n_][kc_], acc[(MB) + m_][n_]);  \
    __builtin_amdgcn_s_setprio(0); }

  bf16x8 af[4][2], bfr[3][2];
  f32x4 acc[8][3];
#pragma unroll
  for (int i = 0; i < 8; ++i)
#pragma unroll
    for (int j = 0; j < 3; ++j) acc[i][j] = (f32x4){0.f, 0.f, 0.f, 0.f};

  // prologue: tile0 -> buf0 (10 loads); B(1) -> buf1 (6); VMC6 forces tile0
  SA(0, 0); SB(0, 0);
  SB(1, 1);
  VMC6; BAR;

#pragma unroll 1
  for (int i = 0; i < 15; ++i) {
    const int t0 = 2 * i;
    // tile t0 (buf0)
    RD_AL(0); RD_B(0); SA(t0 + 1, 1);
    FEN; BAR; MMQ(0); FEN; BAR;
    RD_AH(0); SB(t0 + 2, 0);
    VMC6; BAR; MMQ(4); FEN; BAR;
    // tile t0+1 (buf1)
    RD_AL(1); RD_B(1); SA(t0 + 2, 0);
    FEN; BAR; MMQ(0); FEN; BAR;
    RD_AH(1); SB(t0 + 3, 1);
    VMC6; BAR; MMQ(4); FEN; BAR;
  }
  // tail: t=30 (buf0), t=31 (buf1); A(31) staged in t=30's P1
  RD_AL(0); RD_B(0); SA(31, 1);
  FEN; BAR; MMQ(0); FEN; BAR;
  RD_AH(0);
  VMC0; BAR; MMQ(4); FEN; BAR;
  RD_AL(1); RD_B(1);
  FEN; BAR; MMQ(0); FEN; BAR;
  RD_AH(1);
  FEN; BAR; MMQ(4);

  // epilogue: row = m0 + mi*16 + g4 + r, col = n0 + w*48 + ni*16 + fr
#pragma unroll
  for (int mi = 0; mi < 8; ++mi)
#pragma unroll
    for (int ni = 0; ni < 3; ++ni) {
      const int row0 = m0 + mi * 16 + g4;
      const int cg = n0 + w * 48 + ni * 16 + fr;
      const int bb = row0 >> 11, tl = row0 & 2047;
      if (cg < DMODEL) {
        // Q, pre-scaled
#pragma unroll
        for (int r = 0; r < 4; ++r)
          qb[(size_t)(row0 + r) * DMODEL + cg] = f2bf(acc[mi][ni][r] * SC);
      } else if (cg < 2 * DMODEL) {
        // K -> compact [bh][t][128]
        const int cc = cg - DMODEL;
        const int hh = cc >> 7, d = cc & 127;
        const size_t kbase = (size_t)(bb * NHEADS + hh) * T_SEQ * HDIM;
#pragma unroll
        for (int r = 0; r < 4; ++r)
          kb[kbase + (size_t)(tl + r) * HDIM + d] = f2bf(acc[mi][ni][r]);
      } else {
        // V -> tile-blocked [bh][kt][d][64]
        const int cc = cg - 2 * DMODEL;
        const int hh = cc >> 7, d = cc & 127;
        u16x4 w4;
#pragma unroll
        for (int r = 0; r < 4; ++r) w4[r] = f2bf(acc[mi][ni][r]);
        *(u16x4*)&vb[(size_t)(bb * NHEADS + hh) * T_SEQ * HDIM + (size_t)(tl >> 6) * 8192 +
                     d * 64 + (tl & 63)] = w4;
      }
    }
#undef SA
#undef SB
#undef RD_AL
#undef RD_AH
#undef RD_B
#undef MMQ
}

// ---------------------------------------------------------------------------
// 2-phase out-proj GEMM, 2 blocks/CU: out[4096,2048] = A(bf16) @ Wo^T, f32.
// BM=128, BN=128, BK=64. 256 thr = 4 waves (1m x 4n); per-wave 128x32
// (8mi x 2ni), 32 MFMA/K-tile in 2 phases of 16. LDS 64 KB -> 2 blocks/CU.
// Grid 512 = 8 xcd x (32 mt x 2-nt slice) = exactly 1 round at 2/CU.
// 8 gl_lds/thr/K-tile (A:4, B:4); VMC4 ledger (forces t+1, leaves B(t+2)).
// ---------------------------------------------------------------------------
__global__ __launch_bounds__(256, 2) void gemm_out(const u16* __restrict__ A,
                                                   const u16* __restrict__ W0,
                                                   float* __restrict__ outf) {
  __shared__ u16 lds2[32768];  // A: [0,16384); B: [16384,32768)
  const int tid = threadIdx.x, w = tid >> 6, lane = tid & 63;
  const int fr = lane & 15, g = lane >> 4, g4 = g * 4;
  const int xk = fr & 7;

  const int xcd = blockIdx.x & 7, bi = blockIdx.x >> 3;  // bi 0..63
  const int mt = bi >> 1, nt = xcd * 2 + (bi & 1);
  const int m0 = mt * 128, n0 = nt * 128;

  const int xs0 = (g ^ xk) * 8;
  const int xs1 = xs0 ^ 32;
  const int bRow = w * 32 + fr;

  const u16* pA[4];
  const u16* pB[4];
#pragma unroll
  for (int j = 0; j < 4; ++j) {
    const int gi = j * 256 + tid, row = gi >> 3, ch = (gi & 7) ^ (row & 7);
    pA[j] = A + (size_t)(m0 + row) * DMODEL + ch * 8;
    pB[j] = W0 + (size_t)(n0 + row) * DMODEL + ch * 8;
  }

#define S2A(t, c)                                                                      \
  { _Pragma("unroll") for (int j = 0; j < 4; ++j)                                      \
      gl_lds16(pA[j] + (size_t)(t) * 64, &lds2[(c) * 8192 + j * 2048 + w * 512]); }
#define S2B(t, c)                                                                      \
  { _Pragma("unroll") for (int j = 0; j < 4; ++j)                                      \
      gl_lds16(pB[j] + (size_t)(t) * 64, &lds2[16384 + (c) * 8192 + j * 2048 + w * 512]); }

#define R2AL(c)                                                                        \
  { _Pragma("unroll") for (int m_ = 0; m_ < 4; ++m_) {                                 \
      af[m_][0] = *(const bf16x8*)&lds2[(c) * 8192 + (fr + m_ * 16) * 64 + xs0];       \
      af[m_][1] = *(const bf16x8*)&lds2[(c) * 8192 + (fr + m_ * 16) * 64 + xs1]; } }
#define R2AH(c)                                                                        \
  { _Pragma("unroll") for (int m_ = 0; m_ < 4; ++m_) {                                 \
      af[m_][0] = *(const bf16x8*)&lds2[(c) * 8192 + (fr + 64 + m_ * 16) * 64 + xs0];  \
      af[m_][1] = *(const bf16x8*)&lds2[(c) * 8192 + (fr + 64 + m_ * 16) * 64 + xs1]; } }
#define R2B(c)                                                                         \
  { _Pragma("unroll") for (int n_ = 0; n_ < 2; ++n_) {                                 \
      bfr[n_][0] = *(const bf16x8*)&lds2[16384 + (c) * 8192 + (bRow + n_ * 16) * 64 + xs0]; \
      bfr[n_][1] = *(const bf16x8*)&lds2[16384 + (c) * 8192 + (bRow + n_ * 16) * 64 + xs1]; } }

#define M2(MB)                                                                         \
  { __builtin_amdgcn_s_setprio(1);                                                    \
    _Pragma("unroll") for (int kc_ = 0; kc_ < 2; ++kc_)                                \
      _Pragma("unroll") for (int m_ = 0; m_ < 4; ++m_)                                 \
        _Pragma("unroll") for (int n_ = 0; n_ < 2; ++n_)                               \
          acc[(MB) + m_][n_] = MFMA16(af[m_][kc_], bfr[n_][kc_], acc[(MB) + m_][n_]);  \
    __builtin_amdgcn_s_setprio(0); }

  bf16x8 af[4][2], bfr[2][2];
  f32x4 acc[8][2];
#pragma unroll
  for (int i = 0; i < 8; ++i)
#pragma unroll
    for (int j = 0; j < 2; ++j) acc[i][j] = (f32x4){0.f, 0.f, 0.f, 0.f};

  S2A(0, 0); S2B(0, 0);
  S2B(1, 1);
  VMC4; BAR;

#pragma unroll 1
  for (int i = 0; i < 15; ++i) {
    const int t0 = 2 * i;
    R2AL(0); R2B(0); S2A(t0 + 1, 1);
    FEN; BAR; M2(0); FEN; BAR;
    R2AH(0); S2B(t0 + 2, 0);
    VMC4; BAR; M2(4); FEN; BAR;
    R2AL(1); R2B(1); S2A(t0 + 2, 0);
    FEN; BAR; M2(0); FEN; BAR;
    R2AH(1); S2B(t0 + 3, 1);
    VMC4; BAR; M2(4); FEN; BAR;
  }
  R2AL(0); R2B(0); S2A(31, 1);
  FEN; BAR; M2(0); FEN; BAR;
  R2AH(0);
  VMC0; BAR; M2(4); FEN; BAR;
  R2AL(1); R2B(1);
  FEN; BAR; M2(0); FEN; BAR;
  R2AH(1);
  FEN; BAR; M2(4);

#pragma unroll
  for (int mi = 0; mi < 8; ++mi)
#pragma unroll
    for (int ni = 0; ni < 2; ++ni) {
      const int row0 = m0 + mi * 16 + g4;
      const int c = n0 + w * 32 + ni * 16 + fr;
#pragma unroll
      for (int r = 0; r < 4; ++r)
        outf[(size_t)(row0 + r) * DMODEL + c] = acc[mi][ni][r];
    }
#undef S2A
#undef S2B
#undef R2AL
#undef R2AH
#undef R2B
#undef M2
}

// ---------------------------------------------------------------------------
// Striped flash attention (R16 winner, byte-identical): XCD-locality mapping.
// Grid 768 = 8 xcd x 4 (b,h) pairs x 24 bx; co-resident blocks on one XCD
// share <=4 MB of K/V (L2-resident).
// ---------------------------------------------------------------------------
#define QB 128
#define KVB 64

__global__ __launch_bounds__(512, 4) void attn_kernel(const u16* __restrict__ qb,
                                                      const u16* __restrict__ kb,
                                                      const u16* __restrict__ vb,
                                                      u16* __restrict__ op,
                                                      u16* __restrict__ pO,
                                                      float* __restrict__ pm,
                                                      float* __restrict__ pl) {
  __shared__ u16 lds[40960];  // 80 KB

  const int xcdid = blockIdx.x & 7, j = blockIdx.x >> 3;
  const int p = xcdid * 4 + j / 24;  // (b,h) pair 0..63
  const int bx = j % 24;
  const int h = p & 15, b = p >> 4;

  const bool isglobal = (h & 1) == 0;
  int qt, klo, khi, part = 0;
  bool partial = false;
  if (isglobal) {
    if (bx < 16) {
      qt = 15 - (bx >> 1);
      part = bx & 1;
      partial = true;
      if (part == 0) { klo = 0; khi = 15; } else { klo = 16; khi = 2 * qt + 1; }
    } else {
      qt = 23 - bx;  // 0..7
      klo = 0; khi = 2 * qt + 1;
    }
  } else {
    if (bx >= 16) return;
    qt = 15 - bx;
    const int lo_ = qt * QB - (WINDOW - 1);
    klo = lo_ > 0 ? (lo_ >> 6) : 0;
    khi = 2 * qt + 1;
  }

  const int tid = threadIdx.x, wave = tid >> 6, lane = tid & 63;
  const int fr = lane & 15, g = lane >> 4, g4 = g * 4;
  const int xk = fr & 7;
  const int q0 = qt * QB;
  const int bh = b * NHEADS + h;
  const size_t basek = (size_t)bh * T_SEQ * HDIM;
  const size_t baseo = (size_t)b * T_SEQ * DMODEL + (size_t)h * HDIM;

  bf16x8 qf[4];
  {
    const int qrow = q0 + wave * 16 + fr;
#pragma unroll
    for (int ds = 0; ds < 4; ++ds)
      qf[ds] = *(const bf16x8*)&qb[(size_t)b * T_SEQ * DMODEL + (size_t)qrow * DMODEL +
                                   (size_t)h * HDIM + ds * 32 + g * 8];
  }

  float mrun = -1e30f, lrun = 0.f;
  f32x4 o[8];
#pragma unroll
  for (int dt = 0; dt < 8; ++dt) o[dt] = (f32x4){0.f, 0.f, 0.f, 0.f};

  const int j0 = wave * 2, j1 = wave * 2 + 1;
  const int gi0 = j0 * 64 + lane, gi1 = j1 * 64 + lane;
  const int kr0 = gi0 >> 4, kc0 = (gi0 & 15) ^ (kr0 & 7);
  const int kr1 = gi1 >> 4, kc1 = (gi1 & 15) ^ (kr1 & 7);
  const u16* pK0 = kb + basek + (size_t)kr0 * HDIM + kc0 * 8;
  const u16* pK1 = kb + basek + (size_t)kr1 * HDIM + kc1 * 8;
  const int d0 = gi0 >> 3, vs0 = (gi0 & 7) ^ (d0 & 7);
  const int d1 = gi1 >> 3, vs1 = (gi1 & 7) ^ (d1 & 7);
  const u16* pV0 = vb + basek + (size_t)d0 * 64 + vs0 * 8;
  const u16* pV1 = vb + basek + (size_t)d1 * 64 + vs1 * 8;

#define STAGE(KT, c)                                                                   \
  { gl_lds16(pK0 + (size_t)(KT) * 8192, &lds[(c) * 8192 + j0 * 512]);                  \
    gl_lds16(pK1 + (size_t)(KT) * 8192, &lds[(c) * 8192 + j1 * 512]);                  \
    gl_lds16(pV0 + (size_t)(KT) * 8192, &lds[16384 + (c) * 8192 + j0 * 512]);          \
    gl_lds16(pV1 + (size_t)(KT) * 8192, &lds[16384 + (c) * 8192 + j1 * 512]); }

  u16* Pw = &lds[32768 + wave * 1024];
  const int qg = q0 + wave * 16 + fr;

  STAGE(klo, klo & 1);
  VMC0; BAR;

  for (int kt = klo; kt <= khi; ++kt) {
    const int c = kt & 1;
    const bool more = kt < khi;
    if (more) STAGE(kt + 1, c ^ 1);
    const u16* Kc = &lds[c * 8192];
    const u16* Vc = &lds[16384 + c * 8192];

    f32x4 s[4];
    __builtin_amdgcn_s_setprio(1);
#pragma unroll
    for (int kk = 0; kk < 4; ++kk) {
      f32x4 a = (f32x4){0.f, 0.f, 0.f, 0.f};
#pragma unroll
      for (int ds = 0; ds < 4; ++ds) {
        const int r = kk * 16 + fr;
        bf16x8 kf = *(const bf16x8*)&Kc[r * 128 + (((ds * 4 + g) ^ xk) << 3)];
        a = MFMA16(kf, qf[ds], a);
      }
      s[kk] = a;
    }
    __builtin_amdgcn_s_setprio(0);

    float sv[16];
    float pmax = -1e30f;
#pragma unroll
    for (int kk = 0; kk < 4; ++kk)
#pragma unroll
      for (int reg = 0; reg < 4; ++reg) {
        const int cg = kt * KVB + kk * 16 + g4 + reg;
        const bool allowed = (cg <= qg) && (isglobal || cg >= qg - (WINDOW - 1));
        const float v = allowed ? s[kk][reg] : -1e30f;
        sv[kk * 4 + reg] = v;
        pmax = fmaxf(pmax, v);
      }
    pmax = fmaxf(pmax, __shfl_xor(pmax, 16, 64));
    pmax = fmaxf(pmax, __shfl_xor(pmax, 32, 64));
    const bool resc = !__all(pmax - mrun <= 8.0f);  // T13
    float fac = 1.f;
    if (resc) {
      const float nm = fmaxf(mrun, pmax);
      fac = __expf(mrun - nm);
      mrun = nm;
    }
    float rs = 0.f;
    u16 pb[16];
#pragma unroll
    for (int i = 0; i < 16; ++i) {
      const float p_ = (sv[i] > -5e29f) ? __expf(sv[i] - mrun) : 0.f;
      rs += p_;
      pb[i] = f2bf(p_);
    }
    rs += __shfl_xor(rs, 16, 64);
    rs += __shfl_xor(rs, 32, 64);
    lrun = lrun * fac + rs;

#pragma unroll
    for (int kk = 0; kk < 4; ++kk) {
      u16x4 wv;
      wv[0] = pb[kk * 4]; wv[1] = pb[kk * 4 + 1]; wv[2] = pb[kk * 4 + 2]; wv[3] = pb[kk * 4 + 3];
      *(u16x4*)&Pw[fr * 64 + (((2 * kk + (g >> 1)) ^ xk) << 3) + (g & 1) * 4] = wv;
    }

    if (resc) {
      float ff[4];
#pragma unroll
      for (int r = 0; r < 4; ++r) ff[r] = __shfl(fac, g4 + r, 64);
#pragma unroll
      for (int dt = 0; dt < 8; ++dt)
#pragma unroll
        for (int r = 0; r < 4; ++r) o[dt][r] *= ff[r];
    }

    bf16x8 pf0 = *(const bf16x8*)&Pw[fr * 64 + ((g ^ xk) << 3)];
    bf16x8 pf1 = *(const bf16x8*)&Pw[fr * 64 + (((4 + g) ^ xk) << 3)];
    __builtin_amdgcn_s_setprio(1);
#pragma unroll
    for (int dt = 0; dt < 8; ++dt) {
      const int d = dt * 16 + fr;
      bf16x8 vf0 = *(const bf16x8*)&Vc[d * 64 + ((g ^ xk) << 3)];
      bf16x8 vf1 = *(const bf16x8*)&Vc[d * 64 + (((4 + g) ^ xk) << 3)];
      o[dt] = MFMA16(pf0, vf0, o[dt]);
      o[dt] = MFMA16(pf1, vf1, o[dt]);
    }
    __builtin_amdgcn_s_setprio(0);

    FEN;
    VMC0;
    BAR;
  }

  if (!partial) {
    const float inv = 1.0f / lrun;
    float iv[4];
#pragma unroll
    for (int r = 0; r < 4; ++r) iv[r] = __shfl(inv, g4 + r, 64);
#pragma unroll
    for (int r = 0; r < 4; ++r) {
      const int qrow = q0 + wave * 16 + g4 + r;
#pragma unroll
      for (int dt = 0; dt < 8; ++dt)
        op[baseo + (size_t)qrow * DMODEL + dt * 16 + fr] = f2bf(o[dt][r] * iv[r]);
    }
  } else {
    const int sidx = (((b * 8 + (h >> 1)) * 8 + (qt - 8)) << 1) + part;
    const size_t sb = (size_t)sidx * QB;
#pragma unroll
    for (int r = 0; r < 4; ++r) {
      const size_t row = sb + wave * 16 + g4 + r;
#pragma unroll
      for (int dt = 0; dt < 8; ++dt)
        pO[row * HDIM + dt * 16 + fr] = f2bf(o[dt][r]);
    }
    if (lane < 16) {
      pm[sb + wave * 16 + lane] = mrun;
      pl[sb + wave * 16 + lane] = lrun;
    }
  }
#undef STAGE
}

// ---------------------------------------------------------------------------
// Merge two partials per (b, even h, qt>=8). Grid 128 x 256 thr. Scaled dom.
// ---------------------------------------------------------------------------
__global__ __launch_bounds__(256) void merge_kernel(const u16* __restrict__ pO,
                                                    const float* __restrict__ pm,
                                                    const float* __restrict__ pl,
                                                    u16* __restrict__ op) {
  const int x = blockIdx.x;  // 0..127 = (b*8 + eh)*8 + qt8
  const int qt8 = x & 7, eh = (x >> 3) & 7, b = x >> 6;
  const int h = eh * 2, qt = 8 + qt8;
  const int s0 = x * 2, s1 = s0 + 1;

  for (int i = 0; i < 8; ++i) {
    const int vidx = threadIdx.x + i * 256;  // 0..2047
    const int row = vidx >> 4, d8 = (vidx & 15) * 8;
    const float m0 = pm[s0 * QB + row], m1 = pm[s1 * QB + row];
    const float l0 = pl[s0 * QB + row], l1 = pl[s1 * QB + row];
    const float m = fmaxf(m0, m1);
    const float w0 = __expf(m0 - m), w1 = __expf(m1 - m);
    const float inv = 1.0f / (l0 * w0 + l1 * w1);
    bf16x8 a = *(const bf16x8*)&pO[((size_t)s0 * QB + row) * HDIM + d8];
    bf16x8 c = *(const bf16x8*)&pO[((size_t)s1 * QB + row) * HDIM + d8];
    bf16x8 r;
#pragma unroll
    for (int j = 0; j < 8; ++j)
      r[j] = (short)f2bf((bf2f((u16)a[j]) * w0 + bf2f((u16)c[j]) * w1) * inv);
    *(bf16x8*)&op[((size_t)(b * T_SEQ + qt * QB + row)) * DMODEL + h * HDIM + d8] = r;
  }
}

// ---------------------------------------------------------------------------
extern "C" void kernel_launch(void* const* d_in, const int* in_sizes, int n_in,
                              void* d_out, int out_size, void* d_ws, size_t ws_size,
                              hipStream_t stream) {
  (void)in_sizes; (void)n_in; (void)out_size; (void)ws_size;
  const float* x  = (const float*)d_in[0];
  const float* Wq = (const float*)d_in[1];
  const float* Wk = (const float*)d_in[2];
  const float* Wv = (const float*)d_in[3];
  const float* Wo = (const float*)d_in[4];

  const size_t NX = (size_t)MROWS * DMODEL;
  const size_t NW = (size_t)DMODEL * DMODEL;
  u16* ws  = (u16*)d_ws;
  u16* xb  = ws;                 // bf16 x; later attention output
  u16* wqb = ws + NX;            // [wq|wk|wv] contiguous = Wcat[6144][2048]
  u16* wkb = wqb + NW;
  u16* wvb = wkb + NW;
  u16* wob = wvb + NW;
  u16* qbb = wob + NW;           // qb [4096][2048]
  u16* kbb = qbb + NX;           // kb [32][2048][128]
  u16* vbb = kbb + NX;           // vb [32][32][128][64]

  // partials reuse dead wq/wk region: 256 slots x 128 rows x 128 d
  u16*   pO = wqb;
  float* pm = (float*)(wqb + (size_t)256 * QB * HDIM);
  float* pl = pm + 256 * QB;

  convert_all<<<2048, 256, 0, stream>>>(x, Wq, Wk, Wv, Wo, ws);

  gemm_qkv<<<1024, 256, 0, stream>>>(xb, wqb, qbb, kbb, vbb);

  attn_kernel<<<768, 512, 0, stream>>>(qbb, kbb, vbb, xb, pO, pm, pl);

  merge_kernel<<<128, 256, 0, stream>>>(pO, pm, pl, xb);

  gemm_out<<<512, 256, 0, stream>>>(xb, wob, (float*)d_out);
}

// Round 20
// 210.459 us; speedup vs baseline: 1.0758x; 1.0018x over previous
//
#include <hip/hip_runtime.h>

typedef __attribute__((ext_vector_type(4))) float f32x4;
typedef __attribute__((ext_vector_type(8))) short bf16x8;
typedef __attribute__((ext_vector_type(4))) unsigned short u16x4;
typedef unsigned short u16;

#define MFMA16(a, b, c) __builtin_amdgcn_mfma_f32_16x16x32_bf16((a), (b), (c), 0, 0, 0)

#define T_SEQ 2048
#define DMODEL 2048
#define NHEADS 16
#define HDIM 128
#define WINDOW 256
#define MROWS 4096  // B*T
#define SC 0.08838834764831845f  // 1/sqrt(128)

__device__ __forceinline__ u16 f2bf(float f) {
  union { float f; unsigned u; } v; v.f = f;
  return (u16)((v.u + 0x7FFFu + ((v.u >> 16) & 1u)) >> 16);
}
__device__ __forceinline__ float bf2f(u16 u) {
  union { unsigned u; float f; } v; v.u = ((unsigned)u) << 16;
  return v.f;
}
__device__ __forceinline__ void gl_lds16(const u16* g, u16* l) {
  __builtin_amdgcn_global_load_lds((const __attribute__((address_space(1))) void*)(g),
                                   (__attribute__((address_space(3))) void*)(l), 16, 0, 0);
}

#define BAR __builtin_amdgcn_s_barrier()
#define FEN asm volatile("" ::: "memory")
#define VMC6 asm volatile("s_waitcnt vmcnt(6)" ::: "memory")
#define VMC4 asm volatile("s_waitcnt vmcnt(4)" ::: "memory")
#define VMC0 asm volatile("s_waitcnt vmcnt(0)" ::: "memory")

// ---------------------------------------------------------------------------
// Convert x, Wq, Wk, Wv, Wo (f32) -> contiguous bf16: [xb NX][wq][wk][wv][wo]
// ---------------------------------------------------------------------------
__global__ __launch_bounds__(256) void convert_all(const float* __restrict__ x,
                                                   const float* __restrict__ wq,
                                                   const float* __restrict__ wk,
                                                   const float* __restrict__ wv,
                                                   const float* __restrict__ wo,
                                                   u16* __restrict__ dst) {
  const size_t NX = (size_t)MROWS * DMODEL;
  const size_t NW = (size_t)DMODEL * DMODEL;
  const size_t chunks = (NX + 4 * NW) / 8;
  for (size_t ci = (size_t)blockIdx.x * 256 + threadIdx.x; ci < chunks;
       ci += (size_t)gridDim.x * 256) {
    const size_t off = ci * 8;
    const float* src;
    size_t so;
    if (off < NX) { src = x; so = off; }
    else {
      size_t rem = off - NX;
      if (rem < NW) { src = wq; so = rem; }
      else if (rem < 2 * NW) { src = wk; so = rem - NW; }
      else if (rem < 3 * NW) { src = wv; so = rem - 2 * NW; }
      else { src = wo; so = rem - 3 * NW; }
    }
    f32x4 a = *(const f32x4*)&src[so];
    f32x4 b = *(const f32x4*)&src[so + 4];
    bf16x8 o;
#pragma unroll
    for (int j = 0; j < 4; ++j) { o[j] = (short)f2bf(a[j]); o[j + 4] = (short)f2bf(b[j]); }
    *(bf16x8*)&dst[off] = o;
  }
}

// ---------------------------------------------------------------------------
// 2-phase QKV GEMM, 2 blocks/CU, 3 barriers/K-tile: C[4096,6144] = A @ Wcat^T.
// BM=128, BN=192, BK=64. 256 thr = 4 waves (1m x 4n); per-wave 128x48
// (8mi x 3ni), 48 MFMA/K-tile in 2 phases of 24. LDS 80 KB -> 2 blocks/CU.
// Grid 1024 = 8 xcd x (32 mt x 4-nt slice); W slice 3 MB L2-fits; 2 rounds.
// 10 gl_lds/thr/K-tile (A:4, B:6). Ledger (tile t, buf c=t&1):
//  P1: rd AL+B | SA(t+1)->c^1 | 24 MFMA | BAR_a       (pre-MMQ BAR removed:
//      SA vs old readers covered by prior tile's BAR_c; SB vs RD_B by BAR_a)
//  P2: rd AH   | SB(t+2)->c   | VMC6 | BAR_b | 24 MFMA | BAR_c
// VMC6 forces oldest 10 = B(t+1)+A(t+1); leaves B(t+2). Tail t=30: VMC0.
// Epilogue: qb[4096][2048] (Q pre-scaled), kb[bh][t][128], vb[bh][kt][d][64].
// ---------------------------------------------------------------------------
__global__ __launch_bounds__(256, 2) void gemm_qkv(const u16* __restrict__ A,
                                                   const u16* __restrict__ W,
                                                   u16* __restrict__ qb,
                                                   u16* __restrict__ kb,
                                                   u16* __restrict__ vb) {
  __shared__ u16 lds[40960];  // A: [0,16384) u16; B: [16384,40960) u16
  const int tid = threadIdx.x, w = tid >> 6, lane = tid & 63;
  const int fr = lane & 15, g = lane >> 4, g4 = g * 4;
  const int xk = fr & 7;

  const int xcd = blockIdx.x & 7, bi = blockIdx.x >> 3;  // bi 0..127
  const int mt = bi >> 2, nt = xcd * 4 + (bi & 3);
  const int m0 = mt * 128, n0 = nt * 192;

  const int xs0 = (g ^ xk) * 8;
  const int xs1 = xs0 ^ 32;
  const int bRow = w * 48 + fr;

  // staging sources (pre-swizzled: chunk = slot ^ (row&7))
  const u16* pA[4];
  const u16* pB[6];
#pragma unroll
  for (int j = 0; j < 4; ++j) {
    const int gi = j * 256 + tid, row = gi >> 3, ch = (gi & 7) ^ (row & 7);
    pA[j] = A + (size_t)(m0 + row) * DMODEL + ch * 8;
  }
#pragma unroll
  for (int j = 0; j < 6; ++j) {
    const int gi = j * 256 + tid, row = gi >> 3, ch = (gi & 7) ^ (row & 7);
    pB[j] = W + (size_t)(n0 + row) * DMODEL + ch * 8;
  }

#define SA(t, c)                                                                       \
  { _Pragma("unroll") for (int j = 0; j < 4; ++j)                                      \
      gl_lds16(pA[j] + (size_t)(t) * 64, &lds[(c) * 8192 + j * 2048 + w * 512]); }
#define SB(t, c)                                                                       \
  { _Pragma("unroll") for (int j = 0; j < 6; ++j)                                      \
      gl_lds16(pB[j] + (size_t)(t) * 64, &lds[16384 + (c) * 12288 + j * 2048 + w * 512]); }

#define RD_AL(c)                                                                       \
  { _Pragma("unroll") for (int m_ = 0; m_ < 4; ++m_) {                                 \
      af[m_][0] = *(const bf16x8*)&lds[(c) * 8192 + (fr + m_ * 16) * 64 + xs0];        \
      af[m_][1] = *(const bf16x8*)&lds[(c) * 8192 + (fr + m_ * 16) * 64 + xs1]; } }
#define RD_AH(c)                                                                       \
  { _Pragma("unroll") for (int m_ = 0; m_ < 4; ++m_) {                                 \
      af[m_][0] = *(const bf16x8*)&lds[(c) * 8192 + (fr + 64 + m_ * 16) * 64 + xs0];   \
      af[m_][1] = *(const bf16x8*)&lds[(c) * 8192 + (fr + 64 + m_ * 16) * 64 + xs1]; } }
#define RD_B(c)                                                                        \
  { _Pragma("unroll") for (int n_ = 0; n_ < 3; ++n_) {                                 \
      bfr[n_][0] = *(const bf16x8*)&lds[16384 + (c) * 12288 + (bRow + n_ * 16) * 64 + xs0]; \
      bfr[n_][1] = *(const bf16x8*)&lds[16384 + (c) * 12288 + (bRow + n_ * 16) * 64 + xs1]; } }

#define MMQ(MB)                                                                        \
  { __builtin_amdgcn_s_setprio(1);                                                    \
    _Pragma("unroll") for (int kc_ = 0; kc_ < 2; ++kc_)                                \
      _Pragma("unroll") for (int m_ = 0; m_ < 4; ++m_)                                 \
        _Pragma("unroll") for (int n_ = 0; n_ < 3; ++n_)                               \
          acc[(MB) + m_][n_] = MFMA16(af[m_][kc_], bfr[n_][kc_], acc[(MB) + m_][n_]);  \
    __builtin_amdgcn_s_setprio(0); }

  bf16x8 af[4][2], bfr[3][2];
  f32x4 acc[8][3];
#pragma unroll
  for (int i = 0; i < 8; ++i)
#pragma unroll
    for (int j = 0; j < 3; ++j) acc[i][j] = (f32x4){0.f, 0.f, 0.f, 0.f};

  // prologue: tile0 -> buf0 (10 loads); B(1) -> buf1 (6); VMC6 forces tile0
  SA(0, 0); SB(0, 0);
  SB(1, 1);
  VMC6; BAR;

#pragma unroll 1
  for (int i = 0; i < 15; ++i) {
    const int t0 = 2 * i;
    // tile t0 (buf0)
    RD_AL(0); RD_B(0); SA(t0 + 1, 1);
    FEN; MMQ(0); FEN; BAR;
    RD_AH(0); SB(t0 + 2, 0);
    VMC6; BAR; MMQ(4); FEN; BAR;
    // tile t0+1 (buf1)
    RD_AL(1); RD_B(1); SA(t0 + 2, 0);
    FEN; MMQ(0); FEN; BAR;
    RD_AH(1); SB(t0 + 3, 1);
    VMC6; BAR; MMQ(4); FEN; BAR;
  }
  // tail: t=30 (buf0), t=31 (buf1); A(31) staged in t=30's P1
  RD_AL(0); RD_B(0); SA(31, 1);
  FEN; MMQ(0); FEN; BAR;
  RD_AH(0);
  VMC0; BAR; MMQ(4); FEN; BAR;
  RD_AL(1); RD_B(1);
  FEN; MMQ(0); FEN; BAR;
  RD_AH(1);
  FEN; BAR; MMQ(4);

  // epilogue: row = m0 + mi*16 + g4 + r, col = n0 + w*48 + ni*16 + fr
#pragma unroll
  for (int mi = 0; mi < 8; ++mi)
#pragma unroll
    for (int ni = 0; ni < 3; ++ni) {
      const int row0 = m0 + mi * 16 + g4;
      const int cg = n0 + w * 48 + ni * 16 + fr;
      const int bb = row0 >> 11, tl = row0 & 2047;
      if (cg < DMODEL) {
        // Q, pre-scaled
#pragma unroll
        for (int r = 0; r < 4; ++r)
          qb[(size_t)(row0 + r) * DMODEL + cg] = f2bf(acc[mi][ni][r] * SC);
      } else if (cg < 2 * DMODEL) {
        // K -> compact [bh][t][128]
        const int cc = cg - DMODEL;
        const int hh = cc >> 7, d = cc & 127;
        const size_t kbase = (size_t)(bb * NHEADS + hh) * T_SEQ * HDIM;
#pragma unroll
        for (int r = 0; r < 4; ++r)
          kb[kbase + (size_t)(tl + r) * HDIM + d] = f2bf(acc[mi][ni][r]);
      } else {
        // V -> tile-blocked [bh][kt][d][64]
        const int cc = cg - 2 * DMODEL;
        const int hh = cc >> 7, d = cc & 127;
        u16x4 w4;
#pragma unroll
        for (int r = 0; r < 4; ++r) w4[r] = f2bf(acc[mi][ni][r]);
        *(u16x4*)&vb[(size_t)(bb * NHEADS + hh) * T_SEQ * HDIM + (size_t)(tl >> 6) * 8192 +
                     d * 64 + (tl & 63)] = w4;
      }
    }
#undef SA
#undef SB
#undef RD_AL
#undef RD_AH
#undef RD_B
#undef MMQ
}

// ---------------------------------------------------------------------------
// 2-phase out-proj GEMM, 2 blocks/CU, 3 barriers/K-tile (same transform).
// BM=128, BN=128, BK=64. Grid 512 = 8 xcd x (32 mt x 2-nt) = 1 round at 2/CU.
// 8 gl_lds/thr/K-tile (A:4, B:4); VMC4 ledger (forces t+1, leaves B(t+2)).
// ---------------------------------------------------------------------------
__global__ __launch_bounds__(256, 2) void gemm_out(const u16* __restrict__ A,
                                                   const u16* __restrict__ W0,
                                                   float* __restrict__ outf) {
  __shared__ u16 lds2[32768];  // A: [0,16384); B: [16384,32768)
  const int tid = threadIdx.x, w = tid >> 6, lane = tid & 63;
  const int fr = lane & 15, g = lane >> 4, g4 = g * 4;
  const int xk = fr & 7;

  const int xcd = blockIdx.x & 7, bi = blockIdx.x >> 3;  // bi 0..63
  const int mt = bi >> 1, nt = xcd * 2 + (bi & 1);
  const int m0 = mt * 128, n0 = nt * 128;

  const int xs0 = (g ^ xk) * 8;
  const int xs1 = xs0 ^ 32;
  const int bRow = w * 32 + fr;

  const u16* pA[4];
  const u16* pB[4];
#pragma unroll
  for (int j = 0; j < 4; ++j) {
    const int gi = j * 256 + tid, row = gi >> 3, ch = (gi & 7) ^ (row & 7);
    pA[j] = A + (size_t)(m0 + row) * DMODEL + ch * 8;
    pB[j] = W0 + (size_t)(n0 + row) * DMODEL + ch * 8;
  }

#define S2A(t, c)                                                                      \
  { _Pragma("unroll") for (int j = 0; j < 4; ++j)                                      \
      gl_lds16(pA[j] + (size_t)(t) * 64, &lds2[(c) * 8192 + j * 2048 + w * 512]); }
#define S2B(t, c)                                                                      \
  { _Pragma("unroll") for (int j = 0; j < 4; ++j)                                      \
      gl_lds16(pB[j] + (size_t)(t) * 64, &lds2[16384 + (c) * 8192 + j * 2048 + w * 512]); }

#define R2AL(c)                                                                        \
  { _Pragma("unroll") for (int m_ = 0; m_ < 4; ++m_) {                                 \
      af[m_][0] = *(const bf16x8*)&lds2[(c) * 8192 + (fr + m_ * 16) * 64 + xs0];       \
      af[m_][1] = *(const bf16x8*)&lds2[(c) * 8192 + (fr + m_ * 16) * 64 + xs1]; } }
#define R2AH(c)                                                                        \
  { _Pragma("unroll") for (int m_ = 0; m_ < 4; ++m_) {                                 \
      af[m_][0] = *(const bf16x8*)&lds2[(c) * 8192 + (fr + 64 + m_ * 16) * 64 + xs0];  \
      af[m_][1] = *(const bf16x8*)&lds2[(c) * 8192 + (fr + 64 + m_ * 16) * 64 + xs1]; } }
#define R2B(c)                                                                         \
  { _Pragma("unroll") for (int n_ = 0; n_ < 2; ++n_) {                                 \
      bfr[n_][0] = *(const bf16x8*)&lds2[16384 + (c) * 8192 + (bRow + n_ * 16) * 64 + xs0]; \
      bfr[n_][1] = *(const bf16x8*)&lds2[16384 + (c) * 8192 + (bRow + n_ * 16) * 64 + xs1]; } }

#define M2(MB)                                                                         \
  { __builtin_amdgcn_s_setprio(1);                                                    \
    _Pragma("unroll") for (int kc_ = 0; kc_ < 2; ++kc_)                                \
      _Pragma("unroll") for (int m_ = 0; m_ < 4; ++m_)                                 \
        _Pragma("unroll") for (int n_ = 0; n_ < 2; ++n_)                               \
          acc[(MB) + m_][n_] = MFMA16(af[m_][kc_], bfr[n_][kc_], acc[(MB) + m_][n_]);  \
    __builtin_amdgcn_s_setprio(0); }

  bf16x8 af[4][2], bfr[2][2];
  f32x4 acc[8][2];
#pragma unroll
  for (int i = 0; i < 8; ++i)
#pragma unroll
    for (int j = 0; j < 2; ++j) acc[i][j] = (f32x4){0.f, 0.f, 0.f, 0.f};

  S2A(0, 0); S2B(0, 0);
  S2B(1, 1);
  VMC4; BAR;

#pragma unroll 1
  for (int i = 0; i < 15; ++i) {
    const int t0 = 2 * i;
    R2AL(0); R2B(0); S2A(t0 + 1, 1);
    FEN; M2(0); FEN; BAR;
    R2AH(0); S2B(t0 + 2, 0);
    VMC4; BAR; M2(4); FEN; BAR;
    R2AL(1); R2B(1); S2A(t0 + 2, 0);
    FEN; M2(0); FEN; BAR;
    R2AH(1); S2B(t0 + 3, 1);
    VMC4; BAR; M2(4); FEN; BAR;
  }
  R2AL(0); R2B(0); S2A(31, 1);
  FEN; M2(0); FEN; BAR;
  R2AH(0);
  VMC0; BAR; M2(4); FEN; BAR;
  R2AL(1); R2B(1);
  FEN; M2(0); FEN; BAR;
  R2AH(1);
  FEN; BAR; M2(4);

#pragma unroll
  for (int mi = 0; mi < 8; ++mi)
#pragma unroll
    for (int ni = 0; ni < 2; ++ni) {
      const int row0 = m0 + mi * 16 + g4;
      const int c = n0 + w * 32 + ni * 16 + fr;
#pragma unroll
      for (int r = 0; r < 4; ++r)
        outf[(size_t)(row0 + r) * DMODEL + c] = acc[mi][ni][r];
    }
#undef S2A
#undef S2B
#undef R2AL
#undef R2AH
#undef R2B
#undef M2
}

// ---------------------------------------------------------------------------
// Striped flash attention (R16 winner, byte-identical): XCD-locality mapping.
// Grid 768 = 8 xcd x 4 (b,h) pairs x 24 bx; co-resident blocks on one XCD
// share <=4 MB of K/V (L2-resident).
// ---------------------------------------------------------------------------
#define QB 128
#define KVB 64

__global__ __launch_bounds__(512, 4) void attn_kernel(const u16* __restrict__ qb,
                                                      const u16* __restrict__ kb,
                                                      const u16* __restrict__ vb,
                                                      u16* __restrict__ op,
                                                      u16* __restrict__ pO,
                                                      float* __restrict__ pm,
                                                      float* __restrict__ pl) {
  __shared__ u16 lds[40960];  // 80 KB

  const int xcdid = blockIdx.x & 7, j = blockIdx.x >> 3;
  const int p = xcdid * 4 + j / 24;  // (b,h) pair 0..63
  const int bx = j % 24;
  const int h = p & 15, b = p >> 4;

  const bool isglobal = (h & 1) == 0;
  int qt, klo, khi, part = 0;
  bool partial = false;
  if (isglobal) {
    if (bx < 16) {
      qt = 15 - (bx >> 1);
      part = bx & 1;
      partial = true;
      if (part == 0) { klo = 0; khi = 15; } else { klo = 16; khi = 2 * qt + 1; }
    } else {
      qt = 23 - bx;  // 0..7
      klo = 0; khi = 2 * qt + 1;
    }
  } else {
    if (bx >= 16) return;
    qt = 15 - bx;
    const int lo_ = qt * QB - (WINDOW - 1);
    klo = lo_ > 0 ? (lo_ >> 6) : 0;
    khi = 2 * qt + 1;
  }

  const int tid = threadIdx.x, wave = tid >> 6, lane = tid & 63;
  const int fr = lane & 15, g = lane >> 4, g4 = g * 4;
  const int xk = fr & 7;
  const int q0 = qt * QB;
  const int bh = b * NHEADS + h;
  const size_t basek = (size_t)bh * T_SEQ * HDIM;
  const size_t baseo = (size_t)b * T_SEQ * DMODEL + (size_t)h * HDIM;

  bf16x8 qf[4];
  {
    const int qrow = q0 + wave * 16 + fr;
#pragma unroll
    for (int ds = 0; ds < 4; ++ds)
      qf[ds] = *(const bf16x8*)&qb[(size_t)b * T_SEQ * DMODEL + (size_t)qrow * DMODEL +
                                   (size_t)h * HDIM + ds * 32 + g * 8];
  }

  float mrun = -1e30f, lrun = 0.f;
  f32x4 o[8];
#pragma unroll
  for (int dt = 0; dt < 8; ++dt) o[dt] = (f32x4){0.f, 0.f, 0.f, 0.f};

  const int j0 = wave * 2, j1 = wave * 2 + 1;
  const int gi0 = j0 * 64 + lane, gi1 = j1 * 64 + lane;
  const int kr0 = gi0 >> 4, kc0 = (gi0 & 15) ^ (kr0 & 7);
  const int kr1 = gi1 >> 4, kc1 = (gi1 & 15) ^ (kr1 & 7);
  const u16* pK0 = kb + basek + (size_t)kr0 * HDIM + kc0 * 8;
  const u16* pK1 = kb + basek + (size_t)kr1 * HDIM + kc1 * 8;
  const int d0 = gi0 >> 3, vs0 = (gi0 & 7) ^ (d0 & 7);
  const int d1 = gi1 >> 3, vs1 = (gi1 & 7) ^ (d1 & 7);
  const u16* pV0 = vb + basek + (size_t)d0 * 64 + vs0 * 8;
  const u16* pV1 = vb + basek + (size_t)d1 * 64 + vs1 * 8;

#define STAGE(KT, c)                                                                   \
  { gl_lds16(pK0 + (size_t)(KT) * 8192, &lds[(c) * 8192 + j0 * 512]);                  \
    gl_lds16(pK1 + (size_t)(KT) * 8192, &lds[(c) * 8192 + j1 * 512]);                  \
    gl_lds16(pV0 + (size_t)(KT) * 8192, &lds[16384 + (c) * 8192 + j0 * 512]);          \
    gl_lds16(pV1 + (size_t)(KT) * 8192, &lds[16384 + (c) * 8192 + j1 * 512]); }

  u16* Pw = &lds[32768 + wave * 1024];
  const int qg = q0 + wave * 16 + fr;

  STAGE(klo, klo & 1);
  VMC0; BAR;

  for (int kt = klo; kt <= khi; ++kt) {
    const int c = kt & 1;
    const bool more = kt < khi;
    if (more) STAGE(kt + 1, c ^ 1);
    const u16* Kc = &lds[c * 8192];
    const u16* Vc = &lds[16384 + c * 8192];

    f32x4 s[4];
    __builtin_amdgcn_s_setprio(1);
#pragma unroll
    for (int kk = 0; kk < 4; ++kk) {
      f32x4 a = (f32x4){0.f, 0.f, 0.f, 0.f};
#pragma unroll
      for (int ds = 0; ds < 4; ++ds) {
        const int r = kk * 16 + fr;
        bf16x8 kf = *(const bf16x8*)&Kc[r * 128 + (((ds * 4 + g) ^ xk) << 3)];
        a = MFMA16(kf, qf[ds], a);
      }
      s[kk] = a;
    }
    __builtin_amdgcn_s_setprio(0);

    float sv[16];
    float pmax = -1e30f;
#pragma unroll
    for (int kk = 0; kk < 4; ++kk)
#pragma unroll
      for (int reg = 0; reg < 4; ++reg) {
        const int cg = kt * KVB + kk * 16 + g4 + reg;
        const bool allowed = (cg <= qg) && (isglobal || cg >= qg - (WINDOW - 1));
        const float v = allowed ? s[kk][reg] : -1e30f;
        sv[kk * 4 + reg] = v;
        pmax = fmaxf(pmax, v);
      }
    pmax = fmaxf(pmax, __shfl_xor(pmax, 16, 64));
    pmax = fmaxf(pmax, __shfl_xor(pmax, 32, 64));
    const bool resc = !__all(pmax - mrun <= 8.0f);  // T13
    float fac = 1.f;
    if (resc) {
      const float nm = fmaxf(mrun, pmax);
      fac = __expf(mrun - nm);
      mrun = nm;
    }
    float rs = 0.f;
    u16 pb[16];
#pragma unroll
    for (int i = 0; i < 16; ++i) {
      const float p_ = (sv[i] > -5e29f) ? __expf(sv[i] - mrun) : 0.f;
      rs += p_;
      pb[i] = f2bf(p_);
    }
    rs += __shfl_xor(rs, 16, 64);
    rs += __shfl_xor(rs, 32, 64);
    lrun = lrun * fac + rs;

#pragma unroll
    for (int kk = 0; kk < 4; ++kk) {
      u16x4 wv;
      wv[0] = pb[kk * 4]; wv[1] = pb[kk * 4 + 1]; wv[2] = pb[kk * 4 + 2]; wv[3] = pb[kk * 4 + 3];
      *(u16x4*)&Pw[fr * 64 + (((2 * kk + (g >> 1)) ^ xk) << 3) + (g & 1) * 4] = wv;
    }

    if (resc) {
      float ff[4];
#pragma unroll
      for (int r = 0; r < 4; ++r) ff[r] = __shfl(fac, g4 + r, 64);
#pragma unroll
      for (int dt = 0; dt < 8; ++dt)
#pragma unroll
        for (int r = 0; r < 4; ++r) o[dt][r] *= ff[r];
    }

    bf16x8 pf0 = *(const bf16x8*)&Pw[fr * 64 + ((g ^ xk) << 3)];
    bf16x8 pf1 = *(const bf16x8*)&Pw[fr * 64 + (((4 + g) ^ xk) << 3)];
    __builtin_amdgcn_s_setprio(1);
#pragma unroll
    for (int dt = 0; dt < 8; ++dt) {
      const int d = dt * 16 + fr;
      bf16x8 vf0 = *(const bf16x8*)&Vc[d * 64 + ((g ^ xk) << 3)];
      bf16x8 vf1 = *(const bf16x8*)&Vc[d * 64 + (((4 + g) ^ xk) << 3)];
      o[dt] = MFMA16(pf0, vf0, o[dt]);
      o[dt] = MFMA16(pf1, vf1, o[dt]);
    }
    __builtin_amdgcn_s_setprio(0);

    FEN;
    VMC0;
    BAR;
  }

  if (!partial) {
    const float inv = 1.0f / lrun;
    float iv[4];
#pragma unroll
    for (int r = 0; r < 4; ++r) iv[r] = __shfl(inv, g4 + r, 64);
#pragma unroll
    for (int r = 0; r < 4; ++r) {
      const int qrow = q0 + wave * 16 + g4 + r;
#pragma unroll
      for (int dt = 0; dt < 8; ++dt)
        op[baseo + (size_t)qrow * DMODEL + dt * 16 + fr] = f2bf(o[dt][r] * iv[r]);
    }
  } else {
    const int sidx = (((b * 8 + (h >> 1)) * 8 + (qt - 8)) << 1) + part;
    const size_t sb = (size_t)sidx * QB;
#pragma unroll
    for (int r = 0; r < 4; ++r) {
      const size_t row = sb + wave * 16 + g4 + r;
#pragma unroll
      for (int dt = 0; dt < 8; ++dt)
        pO[row * HDIM + dt * 16 + fr] = f2bf(o[dt][r]);
    }
    if (lane < 16) {
      pm[sb + wave * 16 + lane] = mrun;
      pl[sb + wave * 16 + lane] = lrun;
    }
  }
#undef STAGE
}

// ---------------------------------------------------------------------------
// Merge two partials per (b, even h, qt>=8). Grid 128 x 256 thr. Scaled dom.
// ---------------------------------------------------------------------------
__global__ __launch_bounds__(256) void merge_kernel(const u16* __restrict__ pO,
                                                    const float* __restrict__ pm,
                                                    const float* __restrict__ pl,
                                                    u16* __restrict__ op) {
  const int x = blockIdx.x;  // 0..127 = (b*8 + eh)*8 + qt8
  const int qt8 = x & 7, eh = (x >> 3) & 7, b = x >> 6;
  const int h = eh * 2, qt = 8 + qt8;
  const int s0 = x * 2, s1 = s0 + 1;

  for (int i = 0; i < 8; ++i) {
    const int vidx = threadIdx.x + i * 256;  // 0..2047
    const int row = vidx >> 4, d8 = (vidx & 15) * 8;
    const float m0 = pm[s0 * QB + row], m1 = pm[s1 * QB + row];
    const float l0 = pl[s0 * QB + row], l1 = pl[s1 * QB + row];
    const float m = fmaxf(m0, m1);
    const float w0 = __expf(m0 - m), w1 = __expf(m1 - m);
    const float inv = 1.0f / (l0 * w0 + l1 * w1);
    bf16x8 a = *(const bf16x8*)&pO[((size_t)s0 * QB + row) * HDIM + d8];
    bf16x8 c = *(const bf16x8*)&pO[((size_t)s1 * QB + row) * HDIM + d8];
    bf16x8 r;
#pragma unroll
    for (int j = 0; j < 8; ++j)
      r[j] = (short)f2bf((bf2f((u16)a[j]) * w0 + bf2f((u16)c[j]) * w1) * inv);
    *(bf16x8*)&op[((size_t)(b * T_SEQ + qt * QB + row)) * DMODEL + h * HDIM + d8] = r;
  }
}

// ---------------------------------------------------------------------------
extern "C" void kernel_launch(void* const* d_in, const int* in_sizes, int n_in,
                              void* d_out, int out_size, void* d_ws, size_t ws_size,
                              hipStream_t stream) {
  (void)in_sizes; (void)n_in; (void)out_size; (void)ws_size;
  const float* x  = (const float*)d_in[0];
  const float* Wq = (const float*)d_in[1];
  const float* Wk = (const float*)d_in[2];
  const float* Wv = (const float*)d_in[3];
  const float* Wo = (const float*)d_in[4];

  const size_t NX = (size_t)MROWS * DMODEL;
  const size_t NW = (size_t)DMODEL * DMODEL;
  u16* ws  = (u16*)d_ws;
  u16* xb  = ws;                 // bf16 x; later attention output
  u16* wqb = ws + NX;            // [wq|wk|wv] contiguous = Wcat[6144][2048]
  u16* wkb = wqb + NW;
  u16* wvb = wkb + NW;
  u16* wob = wvb + NW;
  u16* qbb = wob + NW;           // qb [4096][2048]
  u16* kbb = qbb + NX;           // kb [32][2048][128]
  u16* vbb = kbb + NX;           // vb [32][32][128][64]

  // partials reuse dead wq/wk region: 256 slots x 128 rows x 128 d
  u16*   pO = wqb;
  float* pm = (float*)(wqb + (size_t)256 * QB * HDIM);
  float* pl = pm + 256 * QB;

  convert_all<<<2048, 256, 0, stream>>>(x, Wq, Wk, Wv, Wo, ws);

  gemm_qkv<<<1024, 256, 0, stream>>>(xb, wqb, qbb, kbb, vbb);

  attn_kernel<<<768, 512, 0, stream>>>(qbb, kbb, vbb, xb, pO, pm, pl);

  merge_kernel<<<128, 256, 0, stream>>>(pO, pm, pl, xb);

  gemm_out<<<512, 256, 0, stream>>>(xb, wob, (float*)d_out);
}